// Round 1
// baseline (3960.616 us; speedup 1.0000x reference)
//
#include <hip/hip_runtime.h>
#include <math.h>

#define NU 50000
#define NI 50000
#define NT 100000
#define DD 64
#define NBATCH 4096
#define INV_TEMP 5.0f
#define EPS_ 0.2f

#define ND ((long long)NT * DD)   // 6,400,000 floats

// ---------------- SpMM: y[rows[e]] += vals[e] * x[cols[e]] ----------------
__global__ void spmm_kernel(const int* __restrict__ rows, const int* __restrict__ cols,
                            const float* __restrict__ vals, const float* __restrict__ x,
                            float* __restrict__ y, int nEdges) {
    int idx = blockIdx.x * blockDim.x + threadIdx.x;     // < E*64 = 204.8M, fits int
    int total = nEdges * DD;
    if (idx >= total) return;
    int e = idx >> 6;
    int d = idx & 63;
    int r = rows[e], c = cols[e];
    float v = vals[e];
    atomicAdd(&y[r * DD + d], v * x[c * DD + d]);
}

// ---------------- perturb: y += sign(y) * l2norm(noise_row) * EPS ----------------
__global__ void perturb_kernel(float* __restrict__ y, const float* __restrict__ noise) {
    int gid = blockIdx.x * blockDim.x + threadIdx.x;
    int row = gid >> 6;
    int lane = gid & 63;
    if (row >= NT) return;
    int off = row * DD + lane;
    float n = noise[off];
    float s = n * n;
    #pragma unroll
    for (int o = 32; o > 0; o >>= 1) s += __shfl_xor(s, o);
    float norm = fmaxf(sqrtf(s), 1e-12f);
    float v = y[off];
    float sg = (v > 0.f) ? 1.f : ((v < 0.f) ? -1.f : 0.f);
    y[off] = v + sg * (n / norm) * EPS_;
}

// ---------------- unique via flags ----------------
__global__ void unique_kernel(const int* __restrict__ in, int n, int* __restrict__ flags,
                              int* __restrict__ list, int* __restrict__ count) {
    int t = blockIdx.x * blockDim.x + threadIdx.x;
    if (t >= n) return;
    int u = in[t];
    if (atomicExch(&flags[u], 1) == 0) {
        int p = atomicAdd(count, 1);
        list[p] = u;
    }
}

// ---------------- gather + normalize v1 (light_out) & v2 (emb_cl), pos score ----------------
__global__ void gather_cl_kernel(const int* __restrict__ list, const int* __restrict__ count,
                                 int baseRow,
                                 const float* __restrict__ A, const float* __restrict__ B,
                                 const float* __restrict__ C,
                                 float* __restrict__ V1, float* __restrict__ V2,
                                 float* __restrict__ posv) {
    int gid = blockIdx.x * blockDim.x + threadIdx.x;
    int s = gid >> 6;
    int lane = gid & 63;
    if (s >= NBATCH) return;
    int cnt = *count;
    float v1 = 0.f, v2 = 0.f;
    if (s < cnt) {
        int r = (baseRow + list[s]) * DD + lane;
        v1 = (A[r] + B[r] + C[r]) * (1.f / 3.f);
        v2 = B[r];    // emb_cl = layer-0 perturbed output
    }
    float s1 = v1 * v1, s2 = v2 * v2;
    #pragma unroll
    for (int o = 32; o > 0; o >>= 1) { s1 += __shfl_xor(s1, o); s2 += __shfl_xor(s2, o); }
    v1 = v1 / fmaxf(sqrtf(s1), 1e-12f);
    v2 = v2 / fmaxf(sqrtf(s2), 1e-12f);
    V1[s * DD + lane] = v1;
    V2[s * DD + lane] = v2;
    float d = v1 * v2;
    #pragma unroll
    for (int o = 32; o > 0; o >>= 1) d += __shfl_xor(d, o);
    if (lane == 0) posv[s] = __expf(d * INV_TEMP);
}

// ---------------- ttl[i] = sum_j exp(V1[i].V2[j]/T), 64x64 LDS tiles ----------------
__global__ void ttl_kernel(const float* __restrict__ V1, const float* __restrict__ V2,
                           const int* __restrict__ count, float* __restrict__ ttl) {
    __shared__ float s1[64 * 65];
    __shared__ float s2[64 * 65];
    __shared__ float red[4 * 64];
    int cnt = *count;
    int i0 = blockIdx.x * 64;
    int t = threadIdx.x;   // 256
    for (int k = t; k < 64 * 64; k += 256) {
        int i = k >> 6, d = k & 63;
        s1[i * 65 + d] = V1[(i0 + i) * DD + d];
    }
    int li = t & 63;
    int jsub = t >> 6;     // 0..3
    float acc = 0.f;
    int njt = (cnt + 63) >> 6;
    for (int jt = 0; jt < njt; ++jt) {
        __syncthreads();
        for (int k = t; k < 64 * 64; k += 256) {
            int j = k >> 6, d = k & 63;
            s2[j * 65 + d] = V2[(jt * 64 + j) * DD + d];
        }
        __syncthreads();
        for (int jj = 0; jj < 16; ++jj) {
            int j = jsub * 16 + jj;
            if (jt * 64 + j < cnt) {
                float dot = 0.f;
                #pragma unroll
                for (int d = 0; d < 64; ++d)
                    dot += s1[li * 65 + d] * s2[j * 65 + d];
                acc += __expf(dot * INV_TEMP);
            }
        }
    }
    red[jsub * 64 + li] = acc;
    __syncthreads();
    if (t < 64) {
        ttl[i0 + t] = red[t] + red[64 + t] + red[128 + t] + red[192 + t];
    }
}

// ---------------- cl partial: sum of -log(pos/ttl + 1e-5) over valid rows ----------------
__global__ void cl_reduce_kernel(const float* __restrict__ posv, const float* __restrict__ ttl,
                                 const int* __restrict__ count, float* __restrict__ acc) {
    int t = blockIdx.x * blockDim.x + threadIdx.x;
    if (t >= NBATCH) return;
    int cnt = *count;
    float term = 0.f;
    if (t < cnt) term = -logf(posv[t] / ttl[t] + 1e-5f);
    #pragma unroll
    for (int o = 32; o > 0; o >>= 1) term += __shfl_xor(term, o);
    if ((t & 63) == 0) atomicAdd(acc, term);
}

// ---------------- BPR + reg: one wave per batch element ----------------
__global__ void bpr_kernel(const int* __restrict__ users, const int* __restrict__ pos,
                           const int* __restrict__ neg,
                           const float* __restrict__ A, const float* __restrict__ B,
                           const float* __restrict__ C,
                           const float* __restrict__ user_emb, const float* __restrict__ item_emb,
                           float* __restrict__ mf_acc, float* __restrict__ reg_acc) {
    int gid = blockIdx.x * blockDim.x + threadIdx.x;
    int b = gid >> 6;
    int lane = gid & 63;
    if (b >= NBATCH) return;
    int u = users[b], p = pos[b], n = neg[b];
    int ru = u * DD + lane;
    int rp = (NU + p) * DD + lane;
    int rn = (NU + n) * DD + lane;
    float ue = (A[ru] + B[ru] + C[ru]) * (1.f / 3.f);
    float pe = (A[rp] + B[rp] + C[rp]) * (1.f / 3.f);
    float ne = (A[rn] + B[rn] + C[rn]) * (1.f / 3.f);
    float su = ue * ue, sp = pe * pe, sn = ne * ne, dp = ue * pe, dn = ue * ne;
    float u0 = user_emb[u * DD + lane];
    float p0 = item_emb[p * DD + lane];
    float n0 = item_emb[n * DD + lane];
    float rg = u0 * u0 + p0 * p0 + n0 * n0;
    #pragma unroll
    for (int o = 32; o > 0; o >>= 1) {
        su += __shfl_xor(su, o); sp += __shfl_xor(sp, o); sn += __shfl_xor(sn, o);
        dp += __shfl_xor(dp, o); dn += __shfl_xor(dn, o); rg += __shfl_xor(rg, o);
    }
    if (lane == 0) {
        float nu = fmaxf(sqrtf(su), 1e-12f);
        float np_ = fmaxf(sqrtf(sp), 1e-12f);
        float nn_ = fmaxf(sqrtf(sn), 1e-12f);
        float ps = dp / (nu * np_);
        float ns = dn / (nu * nn_);
        float x = ps - ns;
        float sig = 1.f / (1.f + __expf(-x));
        atomicAdd(mf_acc, logf(sig + 1e-6f));
        atomicAdd(reg_acc, rg);
    }
}

// ---------------- finalize ----------------
__global__ void finalize_kernel(const float* __restrict__ mf_acc, const float* __restrict__ reg_acc,
                                const float* __restrict__ clu, const float* __restrict__ cli,
                                const int* __restrict__ cntu, const int* __restrict__ cnti,
                                float* __restrict__ out) {
    if (threadIdx.x == 0 && blockIdx.x == 0) {
        out[0] = -(*mf_acc) / (float)NBATCH;
        out[1] = 0.2f * ((*clu) / (float)(*cntu) + (*cli) / (float)(*cnti));
        out[2] = 1e-4f * 0.5f * (*reg_acc) / (float)NBATCH;
    }
}

extern "C" void kernel_launch(void* const* d_in, const int* in_sizes, int n_in,
                              void* d_out, int out_size, void* d_ws, size_t ws_size,
                              hipStream_t stream) {
    const int*   users     = (const int*)d_in[0];
    const int*   pos_items = (const int*)d_in[1];
    const int*   neg_items = (const int*)d_in[2];
    const float* user_emb  = (const float*)d_in[3];
    const float* item_emb  = (const float*)d_in[4];
    const int*   rows      = (const int*)d_in[5];
    const int*   cols      = (const int*)d_in[6];
    const float* vals      = (const float*)d_in[7];
    const float* noise     = (const float*)d_in[8];
    float* out = (float*)d_out;
    const int E = in_sizes[5];

    // ---- workspace carve (256B aligned) ----
    char* w = (char*)d_ws;
    size_t off = 0;
    auto carve = [&](size_t bytes) { char* p = w + off; off = (off + bytes + 255) & ~(size_t)255; return p; };
    float* bufA = (float*)carve(ND * 4);
    float* bufB = (float*)carve(ND * 4);
    float* bufC = (float*)carve(ND * 4);
    int* flags_u = (int*)carve(NU * 4);
    int* flags_i = (int*)carve(NI * 4);
    int* ulist   = (int*)carve(NBATCH * 4);
    int* ilist   = (int*)carve(NBATCH * 4);
    int* cnts    = (int*)carve(2 * 4);            // [0]=u, [1]=i
    float* V1u = (float*)carve((size_t)NBATCH * DD * 4);
    float* V2u = (float*)carve((size_t)NBATCH * DD * 4);
    float* V1i = (float*)carve((size_t)NBATCH * DD * 4);
    float* V2i = (float*)carve((size_t)NBATCH * DD * 4);
    float* pos_u = (float*)carve(NBATCH * 4);
    float* pos_i = (float*)carve(NBATCH * 4);
    float* ttl_u = (float*)carve(NBATCH * 4);
    float* ttl_i = (float*)carve(NBATCH * 4);
    float* accum = (float*)carve(4 * 4);          // [0]=mf, [1]=reg, [2]=clu, [3]=cli

    // ---- zero scratch that needs it ----
    hipMemsetAsync(flags_u, 0, NU * 4, stream);
    hipMemsetAsync(flags_i, 0, NI * 4, stream);
    hipMemsetAsync(cnts, 0, 2 * 4, stream);
    hipMemsetAsync(accum, 0, 4 * 4, stream);

    // ---- bufA = concat(user_emb, item_emb) ----
    hipMemcpyAsync(bufA, user_emb, (size_t)NU * DD * 4, hipMemcpyDeviceToDevice, stream);
    hipMemcpyAsync(bufA + (size_t)NU * DD, item_emb, (size_t)NI * DD * 4, hipMemcpyDeviceToDevice, stream);

    const int spmmBlocks = (E * DD + 255) / 256;
    const int rowBlocks  = (NT * DD + 255) / 256;    // wave per row
    const int slotBlocks = (NBATCH * DD + 255) / 256;

    // layer 1: B = perturb(spmm(A), noise[0])    -> emb_cl
    hipMemsetAsync(bufB, 0, ND * 4, stream);
    spmm_kernel<<<spmmBlocks, 256, 0, stream>>>(rows, cols, vals, bufA, bufB, E);
    perturb_kernel<<<rowBlocks, 256, 0, stream>>>(bufB, noise + 0 * ND);
    // layer 2: C = perturb(spmm(B), noise[1])
    hipMemsetAsync(bufC, 0, ND * 4, stream);
    spmm_kernel<<<spmmBlocks, 256, 0, stream>>>(rows, cols, vals, bufB, bufC, E);
    perturb_kernel<<<rowBlocks, 256, 0, stream>>>(bufC, noise + 1 * ND);
    // layer 3: A = perturb(spmm(C), noise[2])   (A's emb0 no longer needed)
    hipMemsetAsync(bufA, 0, ND * 4, stream);
    spmm_kernel<<<spmmBlocks, 256, 0, stream>>>(rows, cols, vals, bufC, bufA, E);
    perturb_kernel<<<rowBlocks, 256, 0, stream>>>(bufA, noise + 2 * ND);

    // light_out = (B + C + A)/3  (computed on the fly)

    // ---- unique ----
    unique_kernel<<<(NBATCH + 255) / 256, 256, 0, stream>>>(users, NBATCH, flags_u, ulist, &cnts[0]);
    unique_kernel<<<(NBATCH + 255) / 256, 256, 0, stream>>>(pos_items, NBATCH, flags_i, ilist, &cnts[1]);

    // ---- gather + normalize + pos scores ----
    gather_cl_kernel<<<slotBlocks, 256, 0, stream>>>(ulist, &cnts[0], 0,  bufA, bufB, bufC, V1u, V2u, pos_u);
    gather_cl_kernel<<<slotBlocks, 256, 0, stream>>>(ilist, &cnts[1], NU, bufA, bufB, bufC, V1i, V2i, pos_i);

    // ---- ttl sums ----
    ttl_kernel<<<NBATCH / 64, 256, 0, stream>>>(V1u, V2u, &cnts[0], ttl_u);
    ttl_kernel<<<NBATCH / 64, 256, 0, stream>>>(V1i, V2i, &cnts[1], ttl_i);

    // ---- cl partial sums ----
    cl_reduce_kernel<<<(NBATCH + 255) / 256, 256, 0, stream>>>(pos_u, ttl_u, &cnts[0], &accum[2]);
    cl_reduce_kernel<<<(NBATCH + 255) / 256, 256, 0, stream>>>(pos_i, ttl_i, &cnts[1], &accum[3]);

    // ---- BPR + reg ----
    bpr_kernel<<<slotBlocks, 256, 0, stream>>>(users, pos_items, neg_items, bufA, bufB, bufC,
                                               user_emb, item_emb, &accum[0], &accum[1]);

    // ---- finalize ----
    finalize_kernel<<<1, 64, 0, stream>>>(&accum[0], &accum[1], &accum[2], &accum[3],
                                          &cnts[0], &cnts[1], out);
}

// Round 2
// 1540.574 us; speedup vs baseline: 2.5709x; 2.5709x over previous
//
#include <hip/hip_runtime.h>
#include <math.h>

#define NU 50000
#define NI 50000
#define NT 100000
#define DD 64
#define NBATCH 4096
#define INV_TEMP 5.0f
#define EPS_ 0.2f

#define ND ((long long)NT * DD)   // 6,400,000 floats

// ---------------- CSR build: histogram ----------------
__global__ void hist_kernel(const int* __restrict__ rows, int E, int* __restrict__ deg) {
    int e = blockIdx.x * blockDim.x + threadIdx.x;
    if (e < E) atomicAdd(&deg[rows[e]], 1);
}

// ---------------- CSR build: single-block exclusive scan over deg[NT] ----------------
__global__ void scan_kernel(const int* __restrict__ deg, int* __restrict__ rstart,
                            int* __restrict__ woff) {
    __shared__ int sd[1024];
    __shared__ int carry;
    int t = threadIdx.x;
    if (t == 0) carry = 0;
    __syncthreads();
    for (int base = 0; base < NT; base += 1024) {
        int i = base + t;
        int v = (i < NT) ? deg[i] : 0;
        sd[t] = v;
        __syncthreads();
        #pragma unroll
        for (int o = 1; o < 1024; o <<= 1) {
            int add = (t >= o) ? sd[t - o] : 0;
            __syncthreads();
            sd[t] += add;
            __syncthreads();
        }
        int inc = sd[t];
        int ex = inc - v + carry;
        if (i < NT) { rstart[i] = ex; woff[i] = ex; }
        __syncthreads();
        if (t == 1023) carry += inc;
        __syncthreads();
    }
}

// ---------------- CSR build: scatter edges as int2{col, bits(val)} ----------------
__global__ void scatter_kernel(const int* __restrict__ rows, const int* __restrict__ cols,
                               const float* __restrict__ vals, int E,
                               int* __restrict__ woff, int2* __restrict__ edges) {
    int e = blockIdx.x * blockDim.x + threadIdx.x;
    if (e >= E) return;
    int p = atomicAdd(&woff[rows[e]], 1);
    edges[p] = make_int2(cols[e], __float_as_int(vals[e]));
}

// ---------------- SpMM (CSR, wave per row) + fused perturb ----------------
__global__ void spmm_csr_kernel(const int* __restrict__ rstart, const int* __restrict__ deg,
                                const int2* __restrict__ edges, const float* __restrict__ x,
                                const float* __restrict__ noise, float* __restrict__ y) {
    int gid = blockIdx.x * blockDim.x + threadIdx.x;
    int row = gid >> 6;
    int lane = gid & 63;
    if (row >= NT) return;
    int start = rstart[row];
    int dg = deg[row];
    float acc = 0.f;
    for (int base = 0; base < dg; base += 64) {
        int kk = base + lane;
        int2 ed = (kk < dg) ? edges[start + kk] : make_int2(0, 0);
        int lim = min(64, dg - base);
        for (int j = 0; j < lim; ++j) {
            int c = __shfl(ed.x, j);
            float v = __int_as_float(__shfl(ed.y, j));
            acc += v * x[c * DD + lane];
        }
    }
    // perturb: acc + sign(acc) * (noise_row / ||noise_row||) * EPS
    float nz = noise[row * DD + lane];
    float s = nz * nz;
    #pragma unroll
    for (int o = 32; o > 0; o >>= 1) s += __shfl_xor(s, o);
    float norm = fmaxf(sqrtf(s), 1e-12f);
    float sg = (acc > 0.f) ? 1.f : ((acc < 0.f) ? -1.f : 0.f);
    y[row * DD + lane] = acc + sg * (nz / norm) * EPS_;
}

// ---------------- unique via flags ----------------
__global__ void unique_kernel(const int* __restrict__ in, int n, int* __restrict__ flags,
                              int* __restrict__ list, int* __restrict__ count) {
    int t = blockIdx.x * blockDim.x + threadIdx.x;
    if (t >= n) return;
    int u = in[t];
    if (atomicExch(&flags[u], 1) == 0) {
        int p = atomicAdd(count, 1);
        list[p] = u;
    }
}

// ---------------- gather + normalize v1 (light_out) & v2 (emb_cl), pos score ----------------
__global__ void gather_cl_kernel(const int* __restrict__ list, const int* __restrict__ count,
                                 int baseRow,
                                 const float* __restrict__ A, const float* __restrict__ B,
                                 const float* __restrict__ C,
                                 float* __restrict__ V1, float* __restrict__ V2,
                                 float* __restrict__ posv) {
    int gid = blockIdx.x * blockDim.x + threadIdx.x;
    int s = gid >> 6;
    int lane = gid & 63;
    if (s >= NBATCH) return;
    int cnt = *count;
    float v1 = 0.f, v2 = 0.f;
    if (s < cnt) {
        int r = (baseRow + list[s]) * DD + lane;
        v1 = (A[r] + B[r] + C[r]) * (1.f / 3.f);
        v2 = B[r];    // emb_cl = layer-1 perturbed output
    }
    float s1 = v1 * v1, s2 = v2 * v2;
    #pragma unroll
    for (int o = 32; o > 0; o >>= 1) { s1 += __shfl_xor(s1, o); s2 += __shfl_xor(s2, o); }
    v1 = v1 / fmaxf(sqrtf(s1), 1e-12f);
    v2 = v2 / fmaxf(sqrtf(s2), 1e-12f);
    V1[s * DD + lane] = v1;
    V2[s * DD + lane] = v2;
    float d = v1 * v2;
    #pragma unroll
    for (int o = 32; o > 0; o >>= 1) d += __shfl_xor(d, o);
    if (lane == 0) posv[s] = __expf(d * INV_TEMP);
}

// ---------------- ttl: 64x64 output tile per block, 4x4 register tiling ----------------
// grid (64, 64): blockIdx.x = i-tile, blockIdx.y = j-tile. atomicAdd partials into ttl[i].
__global__ void ttl_kernel(const float* __restrict__ V1, const float* __restrict__ V2,
                           const int* __restrict__ count, float* __restrict__ ttl) {
    __shared__ float sA[64 * 68];   // transposed: [d][i], stride 68 (16B-aligned rows)
    __shared__ float sB[64 * 68];   // transposed: [d][j]
    __shared__ float red[64];
    int cnt = *count;
    int i0 = blockIdx.x * 64;
    int j0 = blockIdx.y * 64;
    if (j0 >= cnt) return;
    int t = threadIdx.x;   // 256
    for (int k = t; k < 64 * 64; k += 256) {
        int r = k >> 6, d = k & 63;
        sA[d * 68 + r] = V1[(i0 + r) * DD + d];
        sB[d * 68 + r] = V2[(j0 + r) * DD + d];
    }
    if (t < 64) red[t] = 0.f;
    __syncthreads();
    int tx = t & 15;        // j-group: cols tx*4..+3
    int ty = t >> 4;        // i-group: rows ty*4..+3
    float acc[4][4] = {{0.f}};
    for (int d = 0; d < 64; ++d) {
        float4 a = *(const float4*)&sA[d * 68 + ty * 4];
        float4 b = *(const float4*)&sB[d * 68 + tx * 4];
        acc[0][0] += a.x * b.x; acc[0][1] += a.x * b.y; acc[0][2] += a.x * b.z; acc[0][3] += a.x * b.w;
        acc[1][0] += a.y * b.x; acc[1][1] += a.y * b.y; acc[1][2] += a.y * b.z; acc[1][3] += a.y * b.w;
        acc[2][0] += a.z * b.x; acc[2][1] += a.z * b.y; acc[2][2] += a.z * b.z; acc[2][3] += a.z * b.w;
        acc[3][0] += a.w * b.x; acc[3][1] += a.w * b.y; acc[3][2] += a.w * b.z; acc[3][3] += a.w * b.w;
    }
    #pragma unroll
    for (int ii = 0; ii < 4; ++ii) {
        float rs = 0.f;
        #pragma unroll
        for (int jj = 0; jj < 4; ++jj) {
            int j = j0 + tx * 4 + jj;
            if (j < cnt) rs += __expf(acc[ii][jj] * INV_TEMP);
        }
        atomicAdd(&red[ty * 4 + ii], rs);
    }
    __syncthreads();
    if (t < 64) atomicAdd(&ttl[i0 + t], red[t]);
}

// ---------------- cl partial: sum of -log(pos/ttl + 1e-5) over valid rows ----------------
__global__ void cl_reduce_kernel(const float* __restrict__ posv, const float* __restrict__ ttl,
                                 const int* __restrict__ count, float* __restrict__ acc) {
    int t = blockIdx.x * blockDim.x + threadIdx.x;
    if (t >= NBATCH) return;
    int cnt = *count;
    float term = 0.f;
    if (t < cnt) term = -logf(posv[t] / ttl[t] + 1e-5f);
    #pragma unroll
    for (int o = 32; o > 0; o >>= 1) term += __shfl_xor(term, o);
    if ((t & 63) == 0) atomicAdd(acc, term);
}

// ---------------- BPR + reg: one wave per batch element ----------------
__global__ void bpr_kernel(const int* __restrict__ users, const int* __restrict__ pos,
                           const int* __restrict__ neg,
                           const float* __restrict__ A, const float* __restrict__ B,
                           const float* __restrict__ C,
                           const float* __restrict__ user_emb, const float* __restrict__ item_emb,
                           float* __restrict__ mf_acc, float* __restrict__ reg_acc) {
    int gid = blockIdx.x * blockDim.x + threadIdx.x;
    int b = gid >> 6;
    int lane = gid & 63;
    if (b >= NBATCH) return;
    int u = users[b], p = pos[b], n = neg[b];
    int ru = u * DD + lane;
    int rp = (NU + p) * DD + lane;
    int rn = (NU + n) * DD + lane;
    float ue = (A[ru] + B[ru] + C[ru]) * (1.f / 3.f);
    float pe = (A[rp] + B[rp] + C[rp]) * (1.f / 3.f);
    float ne = (A[rn] + B[rn] + C[rn]) * (1.f / 3.f);
    float su = ue * ue, sp = pe * pe, sn = ne * ne, dp = ue * pe, dn = ue * ne;
    float u0 = user_emb[u * DD + lane];
    float p0 = item_emb[p * DD + lane];
    float n0 = item_emb[n * DD + lane];
    float rg = u0 * u0 + p0 * p0 + n0 * n0;
    #pragma unroll
    for (int o = 32; o > 0; o >>= 1) {
        su += __shfl_xor(su, o); sp += __shfl_xor(sp, o); sn += __shfl_xor(sn, o);
        dp += __shfl_xor(dp, o); dn += __shfl_xor(dn, o); rg += __shfl_xor(rg, o);
    }
    if (lane == 0) {
        float nu = fmaxf(sqrtf(su), 1e-12f);
        float np_ = fmaxf(sqrtf(sp), 1e-12f);
        float nn_ = fmaxf(sqrtf(sn), 1e-12f);
        float ps = dp / (nu * np_);
        float ns = dn / (nu * nn_);
        float x = ps - ns;
        float sig = 1.f / (1.f + __expf(-x));
        atomicAdd(mf_acc, logf(sig + 1e-6f));
        atomicAdd(reg_acc, rg);
    }
}

// ---------------- finalize ----------------
__global__ void finalize_kernel(const float* __restrict__ mf_acc, const float* __restrict__ reg_acc,
                                const float* __restrict__ clu, const float* __restrict__ cli,
                                const int* __restrict__ cntu, const int* __restrict__ cnti,
                                float* __restrict__ out) {
    if (threadIdx.x == 0 && blockIdx.x == 0) {
        out[0] = -(*mf_acc) / (float)NBATCH;
        out[1] = 0.2f * ((*clu) / (float)(*cntu) + (*cli) / (float)(*cnti));
        out[2] = 1e-4f * 0.5f * (*reg_acc) / (float)NBATCH;
    }
}

extern "C" void kernel_launch(void* const* d_in, const int* in_sizes, int n_in,
                              void* d_out, int out_size, void* d_ws, size_t ws_size,
                              hipStream_t stream) {
    const int*   users     = (const int*)d_in[0];
    const int*   pos_items = (const int*)d_in[1];
    const int*   neg_items = (const int*)d_in[2];
    const float* user_emb  = (const float*)d_in[3];
    const float* item_emb  = (const float*)d_in[4];
    const int*   rows      = (const int*)d_in[5];
    const int*   cols      = (const int*)d_in[6];
    const float* vals      = (const float*)d_in[7];
    const float* noise     = (const float*)d_in[8];
    float* out = (float*)d_out;
    const int E = in_sizes[5];

    // ---- workspace carve (256B aligned) ----
    char* w = (char*)d_ws;
    size_t off = 0;
    auto carve = [&](size_t bytes) { char* p = w + off; off = (off + bytes + 255) & ~(size_t)255; return p; };
    float* bufA = (float*)carve(ND * 4);
    float* bufB = (float*)carve(ND * 4);
    float* bufC = (float*)carve(ND * 4);
    int2*  edges   = (int2*)carve((size_t)E * 8);
    int*   deg     = (int*)carve(NT * 4);
    int*   rstart  = (int*)carve(NT * 4);
    int*   woff    = (int*)carve(NT * 4);
    int* flags_u = (int*)carve(NU * 4);
    int* flags_i = (int*)carve(NI * 4);
    int* ulist   = (int*)carve(NBATCH * 4);
    int* ilist   = (int*)carve(NBATCH * 4);
    int* cnts    = (int*)carve(2 * 4);            // [0]=u, [1]=i
    float* V1u = (float*)carve((size_t)NBATCH * DD * 4);
    float* V2u = (float*)carve((size_t)NBATCH * DD * 4);
    float* V1i = (float*)carve((size_t)NBATCH * DD * 4);
    float* V2i = (float*)carve((size_t)NBATCH * DD * 4);
    float* pos_u = (float*)carve(NBATCH * 4);
    float* pos_i = (float*)carve(NBATCH * 4);
    float* ttl_u = (float*)carve(NBATCH * 4);
    float* ttl_i = (float*)carve(NBATCH * 4);
    float* accum = (float*)carve(4 * 4);          // [0]=mf, [1]=reg, [2]=clu, [3]=cli

    // ---- zero scratch that needs it ----
    hipMemsetAsync(deg, 0, NT * 4, stream);
    hipMemsetAsync(flags_u, 0, NU * 4, stream);
    hipMemsetAsync(flags_i, 0, NI * 4, stream);
    hipMemsetAsync(cnts, 0, 2 * 4, stream);
    hipMemsetAsync(accum, 0, 4 * 4, stream);
    hipMemsetAsync(ttl_u, 0, NBATCH * 4, stream);
    hipMemsetAsync(ttl_i, 0, NBATCH * 4, stream);

    // ---- bufA = concat(user_emb, item_emb) ----
    hipMemcpyAsync(bufA, user_emb, (size_t)NU * DD * 4, hipMemcpyDeviceToDevice, stream);
    hipMemcpyAsync(bufA + (size_t)NU * DD, item_emb, (size_t)NI * DD * 4, hipMemcpyDeviceToDevice, stream);

    const int edgeBlocks = (E + 255) / 256;
    const int rowBlocks  = (NT * DD + 255) / 256;    // wave per row
    const int slotBlocks = (NBATCH * DD + 255) / 256;

    // ---- build CSR (sorted-by-row edge list) ----
    hist_kernel<<<edgeBlocks, 256, 0, stream>>>(rows, E, deg);
    scan_kernel<<<1, 1024, 0, stream>>>(deg, rstart, woff);
    scatter_kernel<<<edgeBlocks, 256, 0, stream>>>(rows, cols, vals, E, woff, edges);

    // ---- 3 propagation layers, perturb fused ----
    spmm_csr_kernel<<<rowBlocks, 256, 0, stream>>>(rstart, deg, edges, bufA, noise + 0 * ND, bufB);
    spmm_csr_kernel<<<rowBlocks, 256, 0, stream>>>(rstart, deg, edges, bufB, noise + 1 * ND, bufC);
    spmm_csr_kernel<<<rowBlocks, 256, 0, stream>>>(rstart, deg, edges, bufC, noise + 2 * ND, bufA);

    // light_out = (B + C + A)/3  (computed on the fly)

    // ---- unique ----
    unique_kernel<<<(NBATCH + 255) / 256, 256, 0, stream>>>(users, NBATCH, flags_u, ulist, &cnts[0]);
    unique_kernel<<<(NBATCH + 255) / 256, 256, 0, stream>>>(pos_items, NBATCH, flags_i, ilist, &cnts[1]);

    // ---- gather + normalize + pos scores ----
    gather_cl_kernel<<<slotBlocks, 256, 0, stream>>>(ulist, &cnts[0], 0,  bufA, bufB, bufC, V1u, V2u, pos_u);
    gather_cl_kernel<<<slotBlocks, 256, 0, stream>>>(ilist, &cnts[1], NU, bufA, bufB, bufC, V1i, V2i, pos_i);

    // ---- ttl sums: grid (i-tiles, j-tiles) ----
    dim3 tgrid(NBATCH / 64, NBATCH / 64);
    ttl_kernel<<<tgrid, 256, 0, stream>>>(V1u, V2u, &cnts[0], ttl_u);
    ttl_kernel<<<tgrid, 256, 0, stream>>>(V1i, V2i, &cnts[1], ttl_i);

    // ---- cl partial sums ----
    cl_reduce_kernel<<<(NBATCH + 255) / 256, 256, 0, stream>>>(pos_u, ttl_u, &cnts[0], &accum[2]);
    cl_reduce_kernel<<<(NBATCH + 255) / 256, 256, 0, stream>>>(pos_i, ttl_i, &cnts[1], &accum[3]);

    // ---- BPR + reg ----
    bpr_kernel<<<slotBlocks, 256, 0, stream>>>(users, pos_items, neg_items, bufA, bufB, bufC,
                                               user_emb, item_emb, &accum[0], &accum[1]);

    // ---- finalize ----
    finalize_kernel<<<1, 64, 0, stream>>>(&accum[0], &accum[1], &accum[2], &accum[3],
                                          &cnts[0], &cnts[1], out);
}